// Round 1
// baseline (492.275 us; speedup 1.0000x reference)
//
#include <hip/hip_runtime.h>
#include <math.h>

// ---------------- constants ----------------
#define BATCH 512
#define DIM 512
#define NCLS 100000
#define NB_TILES 782  // ceil(NCLS/128)
#define S_SCALE 64.0f
#define COS_M 0.8775825618903728f
#define SIN_M 0.479425538604203f
#define TH_C (-0.8775825618903728f)
#define MM_C 0.2397127693021015f
#define CLIP_LO (-1.0f + 1e-7f)
#define CLIP_HI (1.0f - 1e-7f)

typedef __attribute__((ext_vector_type(8))) short bf16x8;
typedef __attribute__((ext_vector_type(4))) float f32x4;

__device__ __forceinline__ unsigned int f2bf(float x) {
    union { float f; unsigned int u; } v;
    v.f = x;
    return (v.u + 0x7fffu + ((v.u >> 16) & 1u)) >> 16;
}
__device__ __forceinline__ unsigned int pack2(float lo, float hi) {
    return f2bf(lo) | (f2bf(hi) << 16);
}

// ---------------- kernel 1: normalize embeddings -> bf16, zero sumexp -------
__global__ void k_norm_e(const float* __restrict__ e, short* __restrict__ ebf,
                         float* __restrict__ sumexpz) {
    int row = blockIdx.x;  // 512 rows
    int tid = threadIdx.x; // 128 threads, 4 floats each
    const float4* p = (const float4*)(e + (size_t)row * DIM);
    float4 v = p[tid];
    float ss = v.x * v.x + v.y * v.y + v.z * v.z + v.w * v.w;
    for (int m = 1; m < 64; m <<= 1) ss += __shfl_xor(ss, m, 64);
    __shared__ float wss[2];
    if ((tid & 63) == 0) wss[tid >> 6] = ss;
    __syncthreads();
    float inv = 1.0f / fmaxf(sqrtf(wss[0] + wss[1]), 1e-12f);
    ushort4 o;
    o.x = (unsigned short)f2bf(v.x * inv);
    o.y = (unsigned short)f2bf(v.y * inv);
    o.z = (unsigned short)f2bf(v.z * inv);
    o.w = (unsigned short)f2bf(v.w * inv);
    ((ushort4*)(ebf + (size_t)row * DIM))[tid] = o;
    if (tid == 0) sumexpz[row] = 0.0f;
}

// ---------------- kernel 2: fused GEMM + w-normalize + margin + sumexp ------
// 512x128 tile (WHOLE batch M=512 per block): W fp32 is read EXACTLY ONCE
// (205 MB vs the previous 4-way mb split's 819 MB through the L3 path).
// A (512 KB bf16) is L2-resident so its per-block re-read is cheap.
// BK=32, reg-staged (global->VGPR->LDS) pipeline, same XOR granule swizzle
// as the 128x128 version (key = (row ^ (row>>2))&3, position-independent
// within 16-row groups). lgkm-only barrier keeps the kc+1 global prefetch
// in flight across the barrier. 512 threads = 8 waves as 4M x 2N, wave tile
// 128x64, acc = 8x4 f32x4 = 128 VGPR -> 2 waves/SIMD.
__global__ __launch_bounds__(512, 2) void k_gemm(
    const short* __restrict__ ebf, const float* __restrict__ wgt,
    const int* __restrict__ labels, float* __restrict__ sumexp,
    float* __restrict__ phiS) {
    __shared__ __align__(16) short As[512 * 32];  // 32 KB
    __shared__ __align__(16) short Bs[128 * 32];  // 8 KB
    __shared__ int sLbl[512];
    __shared__ float sWn[128];

    int nb = blockIdx.x;
    int n0 = nb * 128;

    int tid = threadIdx.x;
    int lane = tid & 63;
    int wv = tid >> 6;   // 0..7
    int wm = wv >> 1;    // 0..3: 128-row block
    int wn = wv & 1;     // 0..1: 64-col block
    int quad = lane >> 4, l16 = lane & 15;

    sLbl[tid] = labels[tid];

    // --- A staging: 4 int4/thread, rows 128*i + (tid>>2), granule tid&3 ---
    int ar = tid >> 2;  // 0..127
    const short* gA = ebf + (size_t)ar * DIM + (tid & 3) * 8;
    int akey = (ar ^ (ar >> 2)) & 3;
    int aw0 = ar * 32 + ((tid & 3) ^ akey) * 8;  // LDS short idx, + i*128*32

    // --- B staging: 2 float4/thread, rows 64*i + (tid>>3), floats (tid&7)*4 --
    int br = tid >> 3;  // 0..63
    int gBo[2];
#pragma unroll
    for (int i = 0; i < 2; ++i) {
        int wr = n0 + 64 * i + br;
        if (wr > NCLS - 1) wr = NCLS - 1;
        gBo[i] = wr * DIM + (tid & 7) * 4;
    }
    int bkey = (br ^ (br >> 2)) & 3;
    int bw0 = br * 32 + (((tid & 7) >> 1) ^ bkey) * 8 + (tid & 1) * 4;

    f32x4 acc[8][4];
#pragma unroll
    for (int i = 0; i < 8; ++i)
#pragma unroll
        for (int j = 0; j < 4; ++j) acc[i][j] = (f32x4){0.f, 0.f, 0.f, 0.f};
    float ssq[2] = {0.f, 0.f};

    // --- fragment read bases (key uniform: row&15 == l16 pattern) ---
    int go = (quad ^ ((l16 ^ (l16 >> 2)) & 3)) * 8;
    int arowb = (wm * 128 + l16) * 32 + go;
    int browb = (wn * 64 + l16) * 32 + go;

    // --- preload kc=0 ---
    int4 ra0 = *(const int4*)(gA);
    int4 ra1 = *(const int4*)(gA + 128 * DIM);
    int4 ra2 = *(const int4*)(gA + 256 * DIM);
    int4 ra3 = *(const int4*)(gA + 384 * DIM);
    float4 rb0 = *(const float4*)(wgt + gBo[0]);
    float4 rb1 = *(const float4*)(wgt + gBo[1]);

#pragma unroll 1
    for (int kc = 0; kc < 16; ++kc) {
        // ---- write staged regs to LDS (cvt W fp32->bf16, track ssq) ----
        *(int4*)&As[aw0] = ra0;
        *(int4*)&As[128 * 32 + aw0] = ra1;
        *(int4*)&As[256 * 32 + aw0] = ra2;
        *(int4*)&As[384 * 32 + aw0] = ra3;
        {
            uint2 p;
            ssq[0] += rb0.x * rb0.x + rb0.y * rb0.y + rb0.z * rb0.z + rb0.w * rb0.w;
            p.x = pack2(rb0.x, rb0.y); p.y = pack2(rb0.z, rb0.w);
            *(uint2*)&Bs[bw0] = p;
            ssq[1] += rb1.x * rb1.x + rb1.y * rb1.y + rb1.z * rb1.z + rb1.w * rb1.w;
            p.x = pack2(rb1.x, rb1.y); p.y = pack2(rb1.z, rb1.w);
            *(uint2*)&Bs[2048 + bw0] = p;
        }
        // ---- prefetch kc+1 (left in flight across the barrier) ----
        if (kc < 15) {
            int ko = (kc + 1) * 32;
            ra0 = *(const int4*)(gA + ko);
            ra1 = *(const int4*)(gA + 128 * DIM + ko);
            ra2 = *(const int4*)(gA + 256 * DIM + ko);
            ra3 = *(const int4*)(gA + 384 * DIM + ko);
            rb0 = *(const float4*)(wgt + gBo[0] + ko);
            rb1 = *(const float4*)(wgt + gBo[1] + ko);
        }
        // wait own LDS writes only; prefetch vmcnt stays outstanding
        asm volatile("s_waitcnt lgkmcnt(0)\n\ts_barrier" ::: "memory");
        // ---- compute: 32 MFMA ----
        {
            bf16x8 bfr[4];
#pragma unroll
            for (int tn = 0; tn < 4; ++tn)
                bfr[tn] = *(const bf16x8*)&Bs[browb + tn * 16 * 32];
#pragma unroll
            for (int tm = 0; tm < 8; ++tm) {
                bf16x8 af = *(const bf16x8*)&As[arowb + tm * 16 * 32];
#pragma unroll
                for (int tn = 0; tn < 4; ++tn)
                    acc[tm][tn] = __builtin_amdgcn_mfma_f32_16x16x32_bf16(
                        af, bfr[tn], acc[tm][tn], 0, 0, 0);
            }
        }
        // frag reads are lgkm-drained before their MFMA uses; plain barrier
        asm volatile("s_barrier" ::: "memory");
    }

    // ---- finalize W norms: reduce ssq over the 8 threads sharing each row --
#pragma unroll
    for (int i = 0; i < 2; ++i) {
        float s = ssq[i];
        s += __shfl_xor(s, 1, 64);
        s += __shfl_xor(s, 2, 64);
        s += __shfl_xor(s, 4, 64);
        if ((lane & 7) == 0)
            sWn[64 * i + br] = 1.0f / fmaxf(sqrtf(s), 1e-12f);
    }
    asm volatile("s_waitcnt lgkmcnt(0)\n\ts_barrier" ::: "memory");

    float wscale[4];
#pragma unroll
    for (int tn = 0; tn < 4; ++tn) wscale[tn] = sWn[wn * 64 + tn * 16 + l16];

    // ---- epilogue: scale, clip, margin on label col, exp, per-row reduce --
#pragma unroll
    for (int tm = 0; tm < 8; ++tm) {
#pragma unroll
        for (int r = 0; r < 4; ++r) {
            int m_local = wm * 128 + tm * 16 + quad * 4 + r;
            int lbl = sLbl[m_local];
            float rs = 0.0f;
#pragma unroll
            for (int tn = 0; tn < 4; ++tn) {
                float c = acc[tm][tn][r] * wscale[tn];
                c = fminf(fmaxf(c, CLIP_LO), CLIP_HI);
                int col = n0 + wn * 64 + tn * 16 + l16;
                float t = c;
                if (col == lbl) {
                    float sn = sqrtf(fmaxf(1.0f - c * c, 0.0f));
                    float ph = c * COS_M - sn * SIN_M;
                    ph = (c > TH_C) ? ph : (c - MM_C);
                    t = ph;
                    phiS[m_local] = S_SCALE * ph;
                }
                rs += (col < NCLS) ? __expf(S_SCALE * t - 64.0f) : 0.0f;
            }
            rs += __shfl_xor(rs, 1, 64);
            rs += __shfl_xor(rs, 2, 64);
            rs += __shfl_xor(rs, 4, 64);
            rs += __shfl_xor(rs, 8, 64);
            if (l16 == ((tm * 4 + r) & 15)) atomicAdd(&sumexp[m_local], rs);
        }
    }
}

// ---------------- kernel 3: nll + mean ----------------
__global__ void k_final(const float* __restrict__ sumexp,
                        const float* __restrict__ phiS,
                        float* __restrict__ out) {
    int tid = threadIdx.x;  // 512
    float nll = 64.0f + logf(sumexp[tid]) - phiS[tid];
    for (int m = 1; m < 64; m <<= 1) nll += __shfl_xor(nll, m, 64);
    __shared__ float ws[8];
    if ((tid & 63) == 0) ws[tid >> 6] = nll;
    __syncthreads();
    if (tid == 0) {
        float s = 0.0f;
        for (int j = 0; j < 8; ++j) s += ws[j];
        out[0] = s / (float)BATCH;
    }
}

// ---------------- launch ----------------
extern "C" void kernel_launch(void* const* d_in, const int* in_sizes, int n_in,
                              void* d_out, int out_size, void* d_ws,
                              size_t ws_size, hipStream_t stream) {
    const float* emb = (const float*)d_in[0];
    const float* wgt = (const float*)d_in[1];
    const int* lbl = (const int*)d_in[2];

    char* ws = (char*)d_ws;
    short* ebf = (short*)ws;                // 524,288 B
    float* sumexp = (float*)(ws + 524288);  // 2048 B
    float* phiS = (float*)(ws + 526336);    // 2048 B

    k_norm_e<<<dim3(BATCH), dim3(128), 0, stream>>>(emb, ebf, sumexp);
    k_gemm<<<dim3(NB_TILES), dim3(512), 0, stream>>>(ebf, wgt, lbl, sumexp, phiS);
    k_final<<<dim3(1), dim3(512), 0, stream>>>(sumexp, phiS, (float*)d_out);
}

// Round 2
// 490.228 us; speedup vs baseline: 1.0042x; 1.0042x over previous
//
#include <hip/hip_runtime.h>
#include <math.h>

// ---------------- constants ----------------
#define BATCH 512
#define DIM 512
#define NCLS 100000
#define NB_TILES 782  // ceil(NCLS/128)
#define S_SCALE 64.0f
#define COS_M 0.8775825618903728f
#define SIN_M 0.479425538604203f
#define TH_C (-0.8775825618903728f)
#define MM_C 0.2397127693021015f
#define CLIP_LO (-1.0f + 1e-7f)
#define CLIP_HI (1.0f - 1e-7f)

typedef __attribute__((ext_vector_type(8))) short bf16x8;
typedef __attribute__((ext_vector_type(4))) float f32x4;

__device__ __forceinline__ unsigned int f2bf(float x) {
    union { float f; unsigned int u; } v;
    v.f = x;
    return (v.u + 0x7fffu + ((v.u >> 16) & 1u)) >> 16;
}
__device__ __forceinline__ unsigned int pack2(float lo, float hi) {
    return f2bf(lo) | (f2bf(hi) << 16);
}

__device__ __forceinline__ void gld_lds16(const void* g, void* l) {
    __builtin_amdgcn_global_load_lds(
        (const __attribute__((address_space(1))) void*)g,
        (__attribute__((address_space(3))) void*)l, 16, 0, 0);
}

// ---------------- kernel 1: normalize embeddings -> bf16, zero sumexp -------
__global__ void k_norm_e(const float* __restrict__ e, short* __restrict__ ebf,
                         float* __restrict__ sumexpz) {
    int row = blockIdx.x;  // 512 rows
    int tid = threadIdx.x; // 128 threads, 4 floats each
    const float4* p = (const float4*)(e + (size_t)row * DIM);
    float4 v = p[tid];
    float ss = v.x * v.x + v.y * v.y + v.z * v.z + v.w * v.w;
    for (int m = 1; m < 64; m <<= 1) ss += __shfl_xor(ss, m, 64);
    __shared__ float wss[2];
    if ((tid & 63) == 0) wss[tid >> 6] = ss;
    __syncthreads();
    float inv = 1.0f / fmaxf(sqrtf(wss[0] + wss[1]), 1e-12f);
    ushort4 o;
    o.x = (unsigned short)f2bf(v.x * inv);
    o.y = (unsigned short)f2bf(v.y * inv);
    o.z = (unsigned short)f2bf(v.z * inv);
    o.w = (unsigned short)f2bf(v.w * inv);
    ((ushort4*)(ebf + (size_t)row * DIM))[tid] = o;
    if (tid == 0) sumexpz[row] = 0.0f;
}

// ---------------- kernel 1b: W fp32 -> bf16 + inv-norms (ONE pass) ---------
// 8 threads per row, element ownership and reduce tree bit-identical to the
// previous fused kernel's ssq path (float4 at j*4 + k*32, shfl_xor 1,2,4),
// so wnorm and wbf match the round-0 numerics exactly.
__global__ void k_wconv(const float* __restrict__ w, short* __restrict__ wbf,
                        float* __restrict__ wnorm) {
    int tid = threadIdx.x;                    // 256
    int row = blockIdx.x * 32 + (tid >> 3);   // 32 rows/block
    int j = tid & 7;
    const float* src = w + (size_t)row * DIM + j * 4;
    short* dst = wbf + (size_t)row * DIM + j * 4;
    float ssq = 0.f;
#pragma unroll
    for (int k = 0; k < 16; ++k) {
        float4 v = *(const float4*)(src + k * 32);
        ssq += v.x * v.x + v.y * v.y + v.z * v.z + v.w * v.w;
        uint2 p;
        p.x = pack2(v.x, v.y);
        p.y = pack2(v.z, v.w);
        *(uint2*)(dst + k * 32) = p;
    }
    ssq += __shfl_xor(ssq, 1, 64);
    ssq += __shfl_xor(ssq, 2, 64);
    ssq += __shfl_xor(ssq, 4, 64);
    if (j == 0) wnorm[row] = 1.0f / fmaxf(sqrtf(ssq), 1e-12f);
}

// ---------------- kernel 2: pure-DMA GEMM + margin + sumexp ----------------
// 128x128 tile, BK=32, both operands bf16 staged via global_load_lds (16B),
// 3-buffer rotation with counted vmcnt(4) (loads stay in flight across
// barriers; never drained to 0 in the loop), ONE barrier per kc.
// XOR granule swizzle realized by pre-swizzling the per-lane GLOBAL source
// (LDS dest stays linear: base + lane*16); key reduces to lane-only
// ((l>>2)^(l>>4))&3 because row = i*64 + wv*16 + (l>>2) and the 16-aligned
// terms vanish mod 4. Fragment reads identical to the round-0 kernel.
__global__ __launch_bounds__(256, 3) void k_gemm2(
    const short* __restrict__ ebf, const short* __restrict__ wbf,
    const float* __restrict__ wnorm, const int* __restrict__ labels,
    float* __restrict__ sumexp, float* __restrict__ phiS) {
    __shared__ __align__(16) short As[3][4096];  // 3 x 8KB
    __shared__ __align__(16) short Bs[3][4096];  // 3 x 8KB
    __shared__ int sLbl[128];

    int bx = blockIdx.x;
    int nb = (bx >> 5) * 8 + (bx & 7);  // mb-siblings share bx%8 (same XCD)
    if (nb >= NB_TILES) return;
    int mb = (bx >> 3) & 3;
    int n0 = nb * 128;

    int tid = threadIdx.x;
    int lane = tid & 63;
    int wv = tid >> 6;
    int wm = wv >> 1, wn = wv & 1;
    int quad = lane >> 4, l16 = lane & 15;

    if (tid < 128) sLbl[tid] = labels[mb * 128 + tid];

    // --- staging addresses (per-lane global, pre-swizzled granule) ---
    int g = (lane & 3) ^ (((lane >> 2) ^ (lane >> 4)) & 3);
    int r0 = wv * 16 + (lane >> 2);  // call-0 row in tile
    int r1 = 64 + r0;                // call-1 row in tile
    const char* gA0 = (const char*)ebf + (size_t)(mb * 128 + r0) * (DIM * 2) + g * 16;
    const char* gA1 = (const char*)ebf + (size_t)(mb * 128 + r1) * (DIM * 2) + g * 16;
    int wr0 = n0 + r0; if (wr0 > NCLS - 1) wr0 = NCLS - 1;
    int wr1 = n0 + r1; if (wr1 > NCLS - 1) wr1 = NCLS - 1;
    const char* gB0 = (const char*)wbf + (size_t)wr0 * (DIM * 2) + g * 16;
    const char* gB1 = (const char*)wbf + (size_t)wr1 * (DIM * 2) + g * 16;
    int ldsw = wv * 1024;  // wave-uniform LDS byte base within a call region

#define STAGE(BUF, KC)                                                    \
    do {                                                                  \
        int kb_ = (KC) * 64;                                              \
        gld_lds16(gA0 + kb_, (char*)&As[BUF][0] + ldsw);                  \
        gld_lds16(gA1 + kb_, (char*)&As[BUF][0] + 4096 + ldsw);           \
        gld_lds16(gB0 + kb_, (char*)&Bs[BUF][0] + ldsw);                  \
        gld_lds16(gB1 + kb_, (char*)&Bs[BUF][0] + 4096 + ldsw);           \
    } while (0)

    f32x4 acc[4][4];
#pragma unroll
    for (int i = 0; i < 4; ++i)
#pragma unroll
        for (int j = 0; j < 4; ++j) acc[i][j] = (f32x4){0.f, 0.f, 0.f, 0.f};

    // --- fragment read bases (identical to round-0) ---
    int go = (quad ^ ((l16 ^ (l16 >> 2)) & 3)) * 8;
    int arowb = (wm * 64 + l16) * 32 + go;
    int browb = (wn * 64 + l16) * 32 + go;

    // --- prologue: stage kc=0,1; drain kc=0 only (kc=1 stays in flight) ---
    STAGE(0, 0);
    STAGE(1, 1);
    asm volatile("s_waitcnt vmcnt(4)\n\ts_barrier" ::: "memory");

#pragma unroll
    for (int kc = 0; kc < 16; ++kc) {
        int cur = kc % 3;
        if (kc + 2 < 16) STAGE((kc + 2) % 3, kc + 2);
        {
            bf16x8 af[4], bfr[4];
#pragma unroll
            for (int t = 0; t < 4; ++t)
                af[t] = *(const bf16x8*)&As[cur][arowb + t * 16 * 32];
#pragma unroll
            for (int t = 0; t < 4; ++t)
                bfr[t] = *(const bf16x8*)&Bs[cur][browb + t * 16 * 32];
#pragma unroll
            for (int tm = 0; tm < 4; ++tm)
#pragma unroll
                for (int tn = 0; tn < 4; ++tn)
                    acc[tm][tn] = __builtin_amdgcn_mfma_f32_16x16x32_bf16(
                        af[tm], bfr[tn], acc[tm][tn], 0, 0, 0);
        }
        // end of iter kc: guarantee tile kc+1 staged (own calls drained,
        // then barrier covers all waves). Newest 4 calls (tile kc+2) stay
        // in flight — counted vmcnt, never 0 mid-loop.
        if (kc < 15) {
            if (kc + 2 < 16)
                asm volatile("s_waitcnt vmcnt(4)\n\ts_barrier" ::: "memory");
            else
                asm volatile("s_waitcnt vmcnt(0)\n\ts_barrier" ::: "memory");
        }
    }
#undef STAGE

    // ---- w scales from precomputed norms ----
    float wscale[4];
#pragma unroll
    for (int tn = 0; tn < 4; ++tn) {
        int col = n0 + wn * 64 + tn * 16 + l16;
        if (col > NCLS - 1) col = NCLS - 1;
        wscale[tn] = wnorm[col];
    }

    // ---- epilogue: scale, clip, margin on label col, exp, per-row reduce --
    float rowsum[16];
#pragma unroll
    for (int i = 0; i < 16; ++i) rowsum[i] = 0.0f;

#pragma unroll
    for (int tm = 0; tm < 4; ++tm) {
#pragma unroll
        for (int r = 0; r < 4; ++r) {
            int m_local = wm * 64 + tm * 16 + quad * 4 + r;
            int lbl = sLbl[m_local];
            float rs = 0.0f;
#pragma unroll
            for (int tn = 0; tn < 4; ++tn) {
                float c = acc[tm][tn][r] * wscale[tn];
                c = fminf(fmaxf(c, CLIP_LO), CLIP_HI);
                int col = n0 + wn * 64 + tn * 16 + l16;
                float t = c;
                if (col == lbl) {
                    float sn = sqrtf(fmaxf(1.0f - c * c, 0.0f));
                    float ph = c * COS_M - sn * SIN_M;
                    ph = (c > TH_C) ? ph : (c - MM_C);
                    t = ph;
                    phiS[mb * 128 + m_local] = S_SCALE * ph;
                }
                float ex = (col < NCLS) ? __expf(S_SCALE * t - 64.0f) : 0.0f;
                rs += ex;
            }
            rowsum[tm * 4 + r] = rs;
        }
    }
#pragma unroll
    for (int idx = 0; idx < 16; ++idx) {
        float v = rowsum[idx];
        v += __shfl_xor(v, 1, 64);
        v += __shfl_xor(v, 2, 64);
        v += __shfl_xor(v, 4, 64);
        v += __shfl_xor(v, 8, 64);
        if (l16 == idx) {
            int tm = idx >> 2, r = idx & 3;
            int m_local = wm * 64 + tm * 16 + quad * 4 + r;
            atomicAdd(&sumexp[mb * 128 + m_local], v);
        }
    }
}

// ---------------- fallback: round-0 fused kernel (small workspace) ----------
__global__ __launch_bounds__(256, 2) void k_gemm_fb(
    const short* __restrict__ ebf, const float* __restrict__ wgt,
    const int* __restrict__ labels, float* __restrict__ sumexp,
    float* __restrict__ phiS) {
    __shared__ __align__(16) short As[128 * 32];
    __shared__ __align__(16) short Bs[128 * 32];
    __shared__ int sLbl[128];
    __shared__ float sWn[128];

    int bx = blockIdx.x;
    int nb = (bx >> 5) * 8 + (bx & 7);
    if (nb >= NB_TILES) return;
    int mb = (bx >> 3) & 3;
    int n0 = nb * 128;

    int tid = threadIdx.x;
    int lane = tid & 63;
    int wv = tid >> 6;
    int wm = wv >> 1, wn = wv & 1;
    int quad = lane >> 4, l16 = lane & 15;

    if (tid < 128) sLbl[tid] = labels[mb * 128 + tid];

    int ar = tid >> 2;
    const short* gA = ebf + (size_t)(mb * 128 + ar) * DIM + (tid & 3) * 8;
    int akey = ((tid >> 2) ^ (tid >> 4)) & 3;
    int aw0 = ar * 32 + ((tid & 3) ^ akey) * 8;

    int br = tid >> 3;
    int gBo[4];
#pragma unroll
    for (int i = 0; i < 4; ++i) {
        int wr = n0 + 32 * i + br;
        if (wr > NCLS - 1) wr = NCLS - 1;
        gBo[i] = wr * DIM + (tid & 7) * 4;
    }
    int bkey = ((tid >> 3) ^ (tid >> 5)) & 3;
    int bw0 = br * 32 + (((tid & 7) >> 1) ^ bkey) * 8 + (tid & 1) * 4;

    f32x4 acc[4][4];
#pragma unroll
    for (int i = 0; i < 4; ++i)
#pragma unroll
        for (int j = 0; j < 4; ++j) acc[i][j] = (f32x4){0.f, 0.f, 0.f, 0.f};
    float ssq[4] = {0.f, 0.f, 0.f, 0.f};

    int go = (quad ^ ((l16 ^ (l16 >> 2)) & 3)) * 8;
    int arowb = (wm * 64 + l16) * 32 + go;
    int browb = (wn * 64 + l16) * 32 + go;

    int4 ra0 = *(const int4*)(gA);
    int4 ra1 = *(const int4*)(gA + 64 * DIM);
    float4 rb0 = *(const float4*)(wgt + gBo[0]);
    float4 rb1 = *(const float4*)(wgt + gBo[1]);
    float4 rb2 = *(const float4*)(wgt + gBo[2]);
    float4 rb3 = *(const float4*)(wgt + gBo[3]);

#pragma unroll 1
    for (int kc = 0; kc < 16; ++kc) {
        *(int4*)&As[aw0] = ra0;
        *(int4*)&As[64 * 32 + aw0] = ra1;
        {
            uint2 p;
            ssq[0] += rb0.x * rb0.x + rb0.y * rb0.y + rb0.z * rb0.z + rb0.w * rb0.w;
            p.x = pack2(rb0.x, rb0.y); p.y = pack2(rb0.z, rb0.w);
            *(uint2*)&Bs[bw0] = p;
            ssq[1] += rb1.x * rb1.x + rb1.y * rb1.y + rb1.z * rb1.z + rb1.w * rb1.w;
            p.x = pack2(rb1.x, rb1.y); p.y = pack2(rb1.z, rb1.w);
            *(uint2*)&Bs[1024 + bw0] = p;
            ssq[2] += rb2.x * rb2.x + rb2.y * rb2.y + rb2.z * rb2.z + rb2.w * rb2.w;
            p.x = pack2(rb2.x, rb2.y); p.y = pack2(rb2.z, rb2.w);
            *(uint2*)&Bs[2048 + bw0] = p;
            ssq[3] += rb3.x * rb3.x + rb3.y * rb3.y + rb3.z * rb3.z + rb3.w * rb3.w;
            p.x = pack2(rb3.x, rb3.y); p.y = pack2(rb3.z, rb3.w);
            *(uint2*)&Bs[3072 + bw0] = p;
        }
        if (kc < 15) {
            int ko = (kc + 1) * 32;
            ra0 = *(const int4*)(gA + ko);
            ra1 = *(const int4*)(gA + 64 * DIM + ko);
            rb0 = *(const float4*)(wgt + gBo[0] + ko);
            rb1 = *(const float4*)(wgt + gBo[1] + ko);
            rb2 = *(const float4*)(wgt + gBo[2] + ko);
            rb3 = *(const float4*)(wgt + gBo[3] + ko);
        }
        asm volatile("s_waitcnt lgkmcnt(0)\n\ts_barrier" ::: "memory");
        {
            bf16x8 af[4], bfr[4];
#pragma unroll
            for (int t = 0; t < 4; ++t)
                af[t] = *(const bf16x8*)&As[arowb + t * 16 * 32];
#pragma unroll
            for (int t = 0; t < 4; ++t)
                bfr[t] = *(const bf16x8*)&Bs[browb + t * 16 * 32];
#pragma unroll
            for (int tm = 0; tm < 4; ++tm)
#pragma unroll
                for (int tn = 0; tn < 4; ++tn)
                    acc[tm][tn] = __builtin_amdgcn_mfma_f32_16x16x32_bf16(
                        af[tm], bfr[tn], acc[tm][tn], 0, 0, 0);
        }
        asm volatile("s_barrier" ::: "memory");
    }

#pragma unroll
    for (int i = 0; i < 4; ++i) {
        float s = ssq[i];
        s += __shfl_xor(s, 1, 64);
        s += __shfl_xor(s, 2, 64);
        s += __shfl_xor(s, 4, 64);
        if ((lane & 7) == 0)
            sWn[32 * i + br] = 1.0f / fmaxf(sqrtf(s), 1e-12f);
    }
    asm volatile("s_waitcnt lgkmcnt(0)\n\ts_barrier" ::: "memory");

    float wscale[4];
#pragma unroll
    for (int tn = 0; tn < 4; ++tn) wscale[tn] = sWn[wn * 64 + tn * 16 + l16];

    float rowsum[16];
#pragma unroll
    for (int i = 0; i < 16; ++i) rowsum[i] = 0.0f;

#pragma unroll
    for (int tm = 0; tm < 4; ++tm) {
#pragma unroll
        for (int r = 0; r < 4; ++r) {
            int m_local = wm * 64 + tm * 16 + quad * 4 + r;
            int lbl = sLbl[m_local];
            float rs = 0.0f;
#pragma unroll
            for (int tn = 0; tn < 4; ++tn) {
                float c = acc[tm][tn][r] * wscale[tn];
                c = fminf(fmaxf(c, CLIP_LO), CLIP_HI);
                int col = n0 + wn * 64 + tn * 16 + l16;
                float t = c;
                if (col == lbl) {
                    float sn = sqrtf(fmaxf(1.0f - c * c, 0.0f));
                    float ph = c * COS_M - sn * SIN_M;
                    ph = (c > TH_C) ? ph : (c - MM_C);
                    t = ph;
                    phiS[mb * 128 + m_local] = S_SCALE * ph;
                }
                float ex = (col < NCLS) ? __expf(S_SCALE * t - 64.0f) : 0.0f;
                rs += ex;
            }
            rowsum[tm * 4 + r] = rs;
        }
    }
#pragma unroll
    for (int idx = 0; idx < 16; ++idx) {
        float v = rowsum[idx];
        v += __shfl_xor(v, 1, 64);
        v += __shfl_xor(v, 2, 64);
        v += __shfl_xor(v, 4, 64);
        v += __shfl_xor(v, 8, 64);
        if (l16 == idx) {
            int tm = idx >> 2, r = idx & 3;
            int m_local = wm * 64 + tm * 16 + quad * 4 + r;
            atomicAdd(&sumexp[mb * 128 + m_local], v);
        }
    }
}

// ---------------- kernel 3: nll + mean ----------------
__global__ void k_final(const float* __restrict__ sumexp,
                        const float* __restrict__ phiS,
                        float* __restrict__ out) {
    int tid = threadIdx.x;  // 512
    float nll = 64.0f + logf(sumexp[tid]) - phiS[tid];
    for (int m = 1; m < 64; m <<= 1) nll += __shfl_xor(nll, m, 64);
    __shared__ float ws[8];
    if ((tid & 63) == 0) ws[tid >> 6] = nll;
    __syncthreads();
    if (tid == 0) {
        float s = 0.0f;
        for (int j = 0; j < 8; ++j) s += ws[j];
        out[0] = s / (float)BATCH;
    }
}

// ---------------- launch ----------------
extern "C" void kernel_launch(void* const* d_in, const int* in_sizes, int n_in,
                              void* d_out, int out_size, void* d_ws,
                              size_t ws_size, hipStream_t stream) {
    const float* emb = (const float*)d_in[0];
    const float* wgt = (const float*)d_in[1];
    const int* lbl = (const int*)d_in[2];

    char* ws = (char*)d_ws;
    short* ebf = (short*)ws;                 // 524,288 B
    float* sumexp = (float*)(ws + 524288);   // 2048 B
    float* phiS = (float*)(ws + 526336);     // 2048 B
    float* wnorm = (float*)(ws + 528384);    // 400,000 B
    short* wbf = (short*)(ws + 1048576);     // 102,400,000 B

    const size_t NEED = 1048576ull + 102400000ull;

    if (ws_size >= NEED) {
        k_wconv<<<dim3(NCLS / 32), dim3(256), 0, stream>>>(wgt, wbf, wnorm);
        k_norm_e<<<dim3(BATCH), dim3(128), 0, stream>>>(emb, ebf, sumexp);
        k_gemm2<<<dim3(3136), dim3(256), 0, stream>>>(ebf, wbf, wnorm, lbl,
                                                      sumexp, phiS);
    } else {
        k_norm_e<<<dim3(BATCH), dim3(128), 0, stream>>>(emb, ebf, sumexp);
        k_gemm_fb<<<dim3(3136), dim3(256), 0, stream>>>(ebf, wgt, lbl, sumexp,
                                                        phiS);
    }
    k_final<<<dim3(1), dim3(512), 0, stream>>>(sumexp, phiS, (float*)d_out);
}

// Round 3
// 482.154 us; speedup vs baseline: 1.0210x; 1.0167x over previous
//
#include <hip/hip_runtime.h>
#include <math.h>

// ---------------- constants ----------------
#define BATCH 512
#define DIM 512
#define NCLS 100000
#define NB_TILES 782  // ceil(NCLS/128)
#define NPART 1564    // NB_TILES * 2 (wn halves)
#define S_SCALE 64.0f
#define COS_M 0.8775825618903728f
#define SIN_M 0.479425538604203f
#define TH_C (-0.8775825618903728f)
#define MM_C 0.2397127693021015f
#define CLIP_LO (-1.0f + 1e-7f)
#define CLIP_HI (1.0f - 1e-7f)

typedef __attribute__((ext_vector_type(8))) short bf16x8;
typedef __attribute__((ext_vector_type(4))) float f32x4;

__device__ __forceinline__ unsigned int f2bf(float x) {
    union { float f; unsigned int u; } v;
    v.f = x;
    return (v.u + 0x7fffu + ((v.u >> 16) & 1u)) >> 16;
}
__device__ __forceinline__ unsigned int pack2(float lo, float hi) {
    return f2bf(lo) | (f2bf(hi) << 16);
}

__device__ __forceinline__ void gld_lds16(const void* g, void* l) {
    __builtin_amdgcn_global_load_lds(
        (const __attribute__((address_space(1))) void*)g,
        (__attribute__((address_space(3))) void*)l, 16, 0, 0);
}

// ---------------- kernel 1: normalize embeddings -> bf16, zero fb sumexp ----
__global__ void k_norm_e(const float* __restrict__ e, short* __restrict__ ebf,
                         float* __restrict__ sumexpz) {
    int row = blockIdx.x;  // 512 rows
    int tid = threadIdx.x; // 128 threads, 4 floats each
    const float4* p = (const float4*)(e + (size_t)row * DIM);
    float4 v = p[tid];
    float ss = v.x * v.x + v.y * v.y + v.z * v.z + v.w * v.w;
    for (int m = 1; m < 64; m <<= 1) ss += __shfl_xor(ss, m, 64);
    __shared__ float wss[2];
    if ((tid & 63) == 0) wss[tid >> 6] = ss;
    __syncthreads();
    float inv = 1.0f / fmaxf(sqrtf(wss[0] + wss[1]), 1e-12f);
    ushort4 o;
    o.x = (unsigned short)f2bf(v.x * inv);
    o.y = (unsigned short)f2bf(v.y * inv);
    o.z = (unsigned short)f2bf(v.z * inv);
    o.w = (unsigned short)f2bf(v.w * inv);
    ((ushort4*)(ebf + (size_t)row * DIM))[tid] = o;
    if (tid == 0) sumexpz[row] = 0.0f;
}

// ---------------- kernel 1b: W fp32 -> bf16 + inv-norms (ONE pass) ---------
// Wave-per-row, fully contiguous: each load instruction covers 1KB of one
// row; stores 512B. Norm reduce = 6-level wave shfl tree.
__global__ void k_wconv(const float* __restrict__ w, short* __restrict__ wbf,
                        float* __restrict__ wnorm) {
    int tid = threadIdx.x;          // 256 = 4 waves
    int wv = tid >> 6, lane = tid & 63;
    int row = blockIdx.x * 4 + wv;  // grid 25000 -> rows 0..99999
    const float4* src = (const float4*)(w + (size_t)row * DIM);
    float4 a = src[lane];
    float4 b = src[64 + lane];
    float ssq = a.x * a.x + a.y * a.y + a.z * a.z + a.w * a.w +
                b.x * b.x + b.y * b.y + b.z * b.z + b.w * b.w;
#pragma unroll
    for (int m = 1; m < 64; m <<= 1) ssq += __shfl_xor(ssq, m, 64);
    ushort4 oa, ob;
    oa.x = (unsigned short)f2bf(a.x);
    oa.y = (unsigned short)f2bf(a.y);
    oa.z = (unsigned short)f2bf(a.z);
    oa.w = (unsigned short)f2bf(a.w);
    ob.x = (unsigned short)f2bf(b.x);
    ob.y = (unsigned short)f2bf(b.y);
    ob.z = (unsigned short)f2bf(b.z);
    ob.w = (unsigned short)f2bf(b.w);
    ushort4* dst = (ushort4*)(wbf + (size_t)row * DIM);
    dst[lane] = oa;
    dst[64 + lane] = ob;
    if (lane == 0) wnorm[row] = 1.0f / fmaxf(sqrtf(ssq), 1e-12f);
}

// ---------------- kernel 2: pure-DMA GEMM + margin + partial sums ----------
// Main loop IDENTICAL to round 2 (128x128 tile, BK=32, global_load_lds,
// 3-buffer rotation, counted vmcnt(4), one barrier/kc).
// Epilogue change: NO atomics. Each wave stores its 64 per-row partial
// sumexp values to partial[(nb*2+wn)*512 + mb*128 + m_local] — every slot
// written exactly once, zero contention. k_rownll reduces the 1564 partials
// per row afterward. (Theory: the 800K device-scope atomicAdds onto 512
// floats were ~150us of serialization — the invariant residue of R0/R1/R2.)
__global__ __launch_bounds__(256, 3) void k_gemm2(
    const short* __restrict__ ebf, const short* __restrict__ wbf,
    const float* __restrict__ wnorm, const int* __restrict__ labels,
    float* __restrict__ partial, float* __restrict__ phiS) {
    __shared__ __align__(16) short As[3][4096];  // 3 x 8KB
    __shared__ __align__(16) short Bs[3][4096];  // 3 x 8KB
    __shared__ int sLbl[128];

    int bx = blockIdx.x;
    int nb = (bx >> 5) * 8 + (bx & 7);  // mb-siblings share bx%8 (same XCD)
    if (nb >= NB_TILES) return;
    int mb = (bx >> 3) & 3;
    int n0 = nb * 128;

    int tid = threadIdx.x;
    int lane = tid & 63;
    int wv = tid >> 6;
    int wm = wv >> 1, wn = wv & 1;
    int quad = lane >> 4, l16 = lane & 15;

    if (tid < 128) sLbl[tid] = labels[mb * 128 + tid];

    // --- staging addresses (per-lane global, pre-swizzled granule) ---
    int g = (lane & 3) ^ (((lane >> 2) ^ (lane >> 4)) & 3);
    int r0 = wv * 16 + (lane >> 2);  // call-0 row in tile
    int r1 = 64 + r0;                // call-1 row in tile
    const char* gA0 = (const char*)ebf + (size_t)(mb * 128 + r0) * (DIM * 2) + g * 16;
    const char* gA1 = (const char*)ebf + (size_t)(mb * 128 + r1) * (DIM * 2) + g * 16;
    int wr0 = n0 + r0; if (wr0 > NCLS - 1) wr0 = NCLS - 1;
    int wr1 = n0 + r1; if (wr1 > NCLS - 1) wr1 = NCLS - 1;
    const char* gB0 = (const char*)wbf + (size_t)wr0 * (DIM * 2) + g * 16;
    const char* gB1 = (const char*)wbf + (size_t)wr1 * (DIM * 2) + g * 16;
    int ldsw = wv * 1024;  // wave-uniform LDS byte base within a call region

#define STAGE(BUF, KC)                                                    \
    do {                                                                  \
        int kb_ = (KC) * 64;                                              \
        gld_lds16(gA0 + kb_, (char*)&As[BUF][0] + ldsw);                  \
        gld_lds16(gA1 + kb_, (char*)&As[BUF][0] + 4096 + ldsw);           \
        gld_lds16(gB0 + kb_, (char*)&Bs[BUF][0] + ldsw);                  \
        gld_lds16(gB1 + kb_, (char*)&Bs[BUF][0] + 4096 + ldsw);           \
    } while (0)

    f32x4 acc[4][4];
#pragma unroll
    for (int i = 0; i < 4; ++i)
#pragma unroll
        for (int j = 0; j < 4; ++j) acc[i][j] = (f32x4){0.f, 0.f, 0.f, 0.f};

    // --- fragment read bases (identical to round-0) ---
    int go = (quad ^ ((l16 ^ (l16 >> 2)) & 3)) * 8;
    int arowb = (wm * 64 + l16) * 32 + go;
    int browb = (wn * 64 + l16) * 32 + go;

    // --- prologue: stage kc=0,1; drain kc=0 only (kc=1 stays in flight) ---
    STAGE(0, 0);
    STAGE(1, 1);
    asm volatile("s_waitcnt vmcnt(4)\n\ts_barrier" ::: "memory");

#pragma unroll
    for (int kc = 0; kc < 16; ++kc) {
        int cur = kc % 3;
        if (kc + 2 < 16) STAGE((kc + 2) % 3, kc + 2);
        {
            bf16x8 af[4], bfr[4];
#pragma unroll
            for (int t = 0; t < 4; ++t)
                af[t] = *(const bf16x8*)&As[cur][arowb + t * 16 * 32];
#pragma unroll
            for (int t = 0; t < 4; ++t)
                bfr[t] = *(const bf16x8*)&Bs[cur][browb + t * 16 * 32];
#pragma unroll
            for (int tm = 0; tm < 4; ++tm)
#pragma unroll
                for (int tn = 0; tn < 4; ++tn)
                    acc[tm][tn] = __builtin_amdgcn_mfma_f32_16x16x32_bf16(
                        af[tm], bfr[tn], acc[tm][tn], 0, 0, 0);
        }
        if (kc < 15) {
            if (kc + 2 < 16)
                asm volatile("s_waitcnt vmcnt(4)\n\ts_barrier" ::: "memory");
            else
                asm volatile("s_waitcnt vmcnt(0)\n\ts_barrier" ::: "memory");
        }
    }
#undef STAGE

    // ---- w scales from precomputed norms ----
    float wscale[4];
#pragma unroll
    for (int tn = 0; tn < 4; ++tn) {
        int col = n0 + wn * 64 + tn * 16 + l16;
        if (col > NCLS - 1) col = NCLS - 1;
        wscale[tn] = wnorm[col];
    }

    // ---- epilogue: scale, clip, margin on label col, exp, per-row reduce --
    float rowsum[16];
#pragma unroll
    for (int i = 0; i < 16; ++i) rowsum[i] = 0.0f;

#pragma unroll
    for (int tm = 0; tm < 4; ++tm) {
#pragma unroll
        for (int r = 0; r < 4; ++r) {
            int m_local = wm * 64 + tm * 16 + quad * 4 + r;
            int lbl = sLbl[m_local];
            float rs = 0.0f;
#pragma unroll
            for (int tn = 0; tn < 4; ++tn) {
                float c = acc[tm][tn][r] * wscale[tn];
                c = fminf(fmaxf(c, CLIP_LO), CLIP_HI);
                int col = n0 + wn * 64 + tn * 16 + l16;
                float t = c;
                if (col == lbl) {
                    float sn = sqrtf(fmaxf(1.0f - c * c, 0.0f));
                    float ph = c * COS_M - sn * SIN_M;
                    ph = (c > TH_C) ? ph : (c - MM_C);
                    t = ph;
                    phiS[mb * 128 + m_local] = S_SCALE * ph;
                }
                float ex = (col < NCLS) ? __expf(S_SCALE * t - 64.0f) : 0.0f;
                rs += ex;
            }
            rowsum[tm * 4 + r] = rs;
        }
    }
    // plain stores: one float per (wave row); slot written exactly once
    float* pbase = partial + (size_t)(nb * 2 + wn) * 512 + mb * 128;
#pragma unroll
    for (int idx = 0; idx < 16; ++idx) {
        float v = rowsum[idx];
        v += __shfl_xor(v, 1, 64);
        v += __shfl_xor(v, 2, 64);
        v += __shfl_xor(v, 4, 64);
        v += __shfl_xor(v, 8, 64);
        if (l16 == idx) {
            int tm = idx >> 2, r = idx & 3;
            int m_local = wm * 64 + tm * 16 + quad * 4 + r;
            pbase[m_local] = v;
        }
    }
}

// ---------------- kernel 2b: reduce partials -> row nll --------------------
__global__ void k_rownll(const float* __restrict__ partial,
                         const float* __restrict__ phiS,
                         float* __restrict__ rownll) {
    int m = blockIdx.x * 64 + threadIdx.x;  // grid 8 x 64
    float s = 0.0f;
#pragma unroll 4
    for (int p = 0; p < NPART; ++p) s += partial[(size_t)p * 512 + m];
    rownll[m] = 64.0f + logf(s) - phiS[m];
}

// ---------------- kernel 3: mean ----------------
__global__ void k_final_mean(const float* __restrict__ rownll,
                             float* __restrict__ out) {
    int tid = threadIdx.x;  // 512
    float nll = rownll[tid];
    for (int m = 1; m < 64; m <<= 1) nll += __shfl_xor(nll, m, 64);
    __shared__ float ws[8];
    if ((tid & 63) == 0) ws[tid >> 6] = nll;
    __syncthreads();
    if (tid == 0) {
        float s = 0.0f;
        for (int j = 0; j < 8; ++j) s += ws[j];
        out[0] = s / (float)BATCH;
    }
}

// ---------------- fallback: round-0 fused kernel (small workspace) ----------
__global__ __launch_bounds__(256, 2) void k_gemm_fb(
    const short* __restrict__ ebf, const float* __restrict__ wgt,
    const int* __restrict__ labels, float* __restrict__ sumexp,
    float* __restrict__ phiS) {
    __shared__ __align__(16) short As[128 * 32];
    __shared__ __align__(16) short Bs[128 * 32];
    __shared__ int sLbl[128];
    __shared__ float sWn[128];

    int bx = blockIdx.x;
    int nb = (bx >> 5) * 8 + (bx & 7);
    if (nb >= NB_TILES) return;
    int mb = (bx >> 3) & 3;
    int n0 = nb * 128;

    int tid = threadIdx.x;
    int lane = tid & 63;
    int wv = tid >> 6;
    int wm = wv >> 1, wn = wv & 1;
    int quad = lane >> 4, l16 = lane & 15;

    if (tid < 128) sLbl[tid] = labels[mb * 128 + tid];

    int ar = tid >> 2;
    const short* gA = ebf + (size_t)(mb * 128 + ar) * DIM + (tid & 3) * 8;
    int akey = ((tid >> 2) ^ (tid >> 4)) & 3;
    int aw0 = ar * 32 + ((tid & 3) ^ akey) * 8;

    int br = tid >> 3;
    int gBo[4];
#pragma unroll
    for (int i = 0; i < 4; ++i) {
        int wr = n0 + 32 * i + br;
        if (wr > NCLS - 1) wr = NCLS - 1;
        gBo[i] = wr * DIM + (tid & 7) * 4;
    }
    int bkey = ((tid >> 3) ^ (tid >> 5)) & 3;
    int bw0 = br * 32 + (((tid & 7) >> 1) ^ bkey) * 8 + (tid & 1) * 4;

    f32x4 acc[4][4];
#pragma unroll
    for (int i = 0; i < 4; ++i)
#pragma unroll
        for (int j = 0; j < 4; ++j) acc[i][j] = (f32x4){0.f, 0.f, 0.f, 0.f};
    float ssq[4] = {0.f, 0.f, 0.f, 0.f};

    int go = (quad ^ ((l16 ^ (l16 >> 2)) & 3)) * 8;
    int arowb = (wm * 64 + l16) * 32 + go;
    int browb = (wn * 64 + l16) * 32 + go;

    int4 ra0 = *(const int4*)(gA);
    int4 ra1 = *(const int4*)(gA + 64 * DIM);
    float4 rb0 = *(const float4*)(wgt + gBo[0]);
    float4 rb1 = *(const float4*)(wgt + gBo[1]);
    float4 rb2 = *(const float4*)(wgt + gBo[2]);
    float4 rb3 = *(const float4*)(wgt + gBo[3]);

#pragma unroll 1
    for (int kc = 0; kc < 16; ++kc) {
        *(int4*)&As[aw0] = ra0;
        *(int4*)&As[64 * 32 + aw0] = ra1;
        {
            uint2 p;
            ssq[0] += rb0.x * rb0.x + rb0.y * rb0.y + rb0.z * rb0.z + rb0.w * rb0.w;
            p.x = pack2(rb0.x, rb0.y); p.y = pack2(rb0.z, rb0.w);
            *(uint2*)&Bs[bw0] = p;
            ssq[1] += rb1.x * rb1.x + rb1.y * rb1.y + rb1.z * rb1.z + rb1.w * rb1.w;
            p.x = pack2(rb1.x, rb1.y); p.y = pack2(rb1.z, rb1.w);
            *(uint2*)&Bs[1024 + bw0] = p;
            ssq[2] += rb2.x * rb2.x + rb2.y * rb2.y + rb2.z * rb2.z + rb2.w * rb2.w;
            p.x = pack2(rb2.x, rb2.y); p.y = pack2(rb2.z, rb2.w);
            *(uint2*)&Bs[2048 + bw0] = p;
            ssq[3] += rb3.x * rb3.x + rb3.y * rb3.y + rb3.z * rb3.z + rb3.w * rb3.w;
            p.x = pack2(rb3.x, rb3.y); p.y = pack2(rb3.z, rb3.w);
            *(uint2*)&Bs[3072 + bw0] = p;
        }
        if (kc < 15) {
            int ko = (kc + 1) * 32;
            ra0 = *(const int4*)(gA + ko);
            ra1 = *(const int4*)(gA + 64 * DIM + ko);
            rb0 = *(const float4*)(wgt + gBo[0] + ko);
            rb1 = *(const float4*)(wgt + gBo[1] + ko);
            rb2 = *(const float4*)(wgt + gBo[2] + ko);
            rb3 = *(const float4*)(wgt + gBo[3] + ko);
        }
        asm volatile("s_waitcnt lgkmcnt(0)\n\ts_barrier" ::: "memory");
        {
            bf16x8 af[4], bfr[4];
#pragma unroll
            for (int t = 0; t < 4; ++t)
                af[t] = *(const bf16x8*)&As[arowb + t * 16 * 32];
#pragma unroll
            for (int t = 0; t < 4; ++t)
                bfr[t] = *(const bf16x8*)&Bs[browb + t * 16 * 32];
#pragma unroll
            for (int tm = 0; tm < 4; ++tm)
#pragma unroll
                for (int tn = 0; tn < 4; ++tn)
                    acc[tm][tn] = __builtin_amdgcn_mfma_f32_16x16x32_bf16(
                        af[tm], bfr[tn], acc[tm][tn], 0, 0, 0);
        }
        asm volatile("s_barrier" ::: "memory");
    }

#pragma unroll
    for (int i = 0; i < 4; ++i) {
        float s = ssq[i];
        s += __shfl_xor(s, 1, 64);
        s += __shfl_xor(s, 2, 64);
        s += __shfl_xor(s, 4, 64);
        if ((lane & 7) == 0)
            sWn[32 * i + br] = 1.0f / fmaxf(sqrtf(s), 1e-12f);
    }
    asm volatile("s_waitcnt lgkmcnt(0)\n\ts_barrier" ::: "memory");

    float wscale[4];
#pragma unroll
    for (int tn = 0; tn < 4; ++tn) wscale[tn] = sWn[wn * 64 + tn * 16 + l16];

    float rowsum[16];
#pragma unroll
    for (int i = 0; i < 16; ++i) rowsum[i] = 0.0f;

#pragma unroll
    for (int tm = 0; tm < 4; ++tm) {
#pragma unroll
        for (int r = 0; r < 4; ++r) {
            int m_local = wm * 64 + tm * 16 + quad * 4 + r;
            int lbl = sLbl[m_local];
            float rs = 0.0f;
#pragma unroll
            for (int tn = 0; tn < 4; ++tn) {
                float c = acc[tm][tn][r] * wscale[tn];
                c = fminf(fmaxf(c, CLIP_LO), CLIP_HI);
                int col = n0 + wn * 64 + tn * 16 + l16;
                float t = c;
                if (col == lbl) {
                    float sn = sqrtf(fmaxf(1.0f - c * c, 0.0f));
                    float ph = c * COS_M - sn * SIN_M;
                    ph = (c > TH_C) ? ph : (c - MM_C);
                    t = ph;
                    phiS[mb * 128 + m_local] = S_SCALE * ph;
                }
                float ex = (col < NCLS) ? __expf(S_SCALE * t - 64.0f) : 0.0f;
                rs += ex;
            }
            rowsum[tm * 4 + r] = rs;
        }
    }
#pragma unroll
    for (int idx = 0; idx < 16; ++idx) {
        float v = rowsum[idx];
        v += __shfl_xor(v, 1, 64);
        v += __shfl_xor(v, 2, 64);
        v += __shfl_xor(v, 4, 64);
        v += __shfl_xor(v, 8, 64);
        if (l16 == idx) {
            int tm = idx >> 2, r = idx & 3;
            int m_local = wm * 64 + tm * 16 + quad * 4 + r;
            atomicAdd(&sumexp[mb * 128 + m_local], v);
        }
    }
}

__global__ void k_final_fb(const float* __restrict__ sumexp,
                           const float* __restrict__ phiS,
                           float* __restrict__ out) {
    int tid = threadIdx.x;  // 512
    float nll = 64.0f + logf(sumexp[tid]) - phiS[tid];
    for (int m = 1; m < 64; m <<= 1) nll += __shfl_xor(nll, m, 64);
    __shared__ float ws[8];
    if ((tid & 63) == 0) ws[tid >> 6] = nll;
    __syncthreads();
    if (tid == 0) {
        float s = 0.0f;
        for (int j = 0; j < 8; ++j) s += ws[j];
        out[0] = s / (float)BATCH;
    }
}

// ---------------- launch ----------------
extern "C" void kernel_launch(void* const* d_in, const int* in_sizes, int n_in,
                              void* d_out, int out_size, void* d_ws,
                              size_t ws_size, hipStream_t stream) {
    const float* emb = (const float*)d_in[0];
    const float* wgt = (const float*)d_in[1];
    const int* lbl = (const int*)d_in[2];

    char* ws = (char*)d_ws;
    short* ebf = (short*)ws;                   // 524,288 B
    float* phiS = (float*)(ws + 524288);       // 2,048 B
    float* rownll = (float*)(ws + 526336);     // 2,048 B
    float* sumexp_fb = (float*)(ws + 528384);  // 2,048 B
    float* wnorm = (float*)(ws + 532480);      // 400,000 B -> ends 932,480
    float* partial = (float*)(ws + 1048576);   // 3,203,072 B -> ends 4,251,648
    short* wbf = (short*)(ws + 4251648);       // 102,400,000 B

    const size_t NEED = 4251648ull + 102400000ull;

    if (ws_size >= NEED) {
        k_wconv<<<dim3(NCLS / 4), dim3(256), 0, stream>>>(wgt, wbf, wnorm);
        k_norm_e<<<dim3(BATCH), dim3(128), 0, stream>>>(emb, ebf, sumexp_fb);
        k_gemm2<<<dim3(3136), dim3(256), 0, stream>>>(ebf, wbf, wnorm, lbl,
                                                      partial, phiS);
        k_rownll<<<dim3(8), dim3(64), 0, stream>>>(partial, phiS, rownll);
        k_final_mean<<<dim3(1), dim3(512), 0, stream>>>(rownll, (float*)d_out);
    } else {
        k_norm_e<<<dim3(BATCH), dim3(128), 0, stream>>>(emb, ebf, sumexp_fb);
        k_gemm_fb<<<dim3(3136), dim3(256), 0, stream>>>(ebf, wgt, lbl,
                                                        sumexp_fb, phiS);
        k_final_fb<<<dim3(1), dim3(512), 0, stream>>>(sumexp_fb, phiS,
                                                      (float*)d_out);
    }
}

// Round 4
// 378.439 us; speedup vs baseline: 1.3008x; 1.2741x over previous
//
#include <hip/hip_runtime.h>
#include <math.h>

// ---------------- constants ----------------
#define BATCH 512
#define DIM 512
#define NCLS 100000
#define NB_TILES 391  // ceil(NCLS/256) for the 256-wide N tile
#define NPART 1564    // NB_TILES * 4 (wn quarters), ascending 64-col groups
#define NB_TILES_FB 782
#define S_SCALE 64.0f
#define COS_M 0.8775825618903728f
#define SIN_M 0.479425538604203f
#define TH_C (-0.8775825618903728f)
#define MM_C 0.2397127693021015f
#define CLIP_LO (-1.0f + 1e-7f)
#define CLIP_HI (1.0f - 1e-7f)

typedef __attribute__((ext_vector_type(8))) short bf16x8;
typedef __attribute__((ext_vector_type(4))) float f32x4;

__device__ __forceinline__ unsigned int f2bf(float x) {
    union { float f; unsigned int u; } v;
    v.f = x;
    return (v.u + 0x7fffu + ((v.u >> 16) & 1u)) >> 16;
}
__device__ __forceinline__ unsigned int pack2(float lo, float hi) {
    return f2bf(lo) | (f2bf(hi) << 16);
}

__device__ __forceinline__ void gld_lds16(const void* g, void* l) {
    __builtin_amdgcn_global_load_lds(
        (const __attribute__((address_space(1))) void*)g,
        (__attribute__((address_space(3))) void*)l, 16, 0, 0);
}

// ---------------- kernel 1: normalize embeddings -> bf16, zero fb sumexp ----
__global__ void k_norm_e(const float* __restrict__ e, short* __restrict__ ebf,
                         float* __restrict__ sumexpz) {
    int row = blockIdx.x;  // 512 rows
    int tid = threadIdx.x; // 128 threads, 4 floats each
    const float4* p = (const float4*)(e + (size_t)row * DIM);
    float4 v = p[tid];
    float ss = v.x * v.x + v.y * v.y + v.z * v.z + v.w * v.w;
    for (int m = 1; m < 64; m <<= 1) ss += __shfl_xor(ss, m, 64);
    __shared__ float wss[2];
    if ((tid & 63) == 0) wss[tid >> 6] = ss;
    __syncthreads();
    float inv = 1.0f / fmaxf(sqrtf(wss[0] + wss[1]), 1e-12f);
    ushort4 o;
    o.x = (unsigned short)f2bf(v.x * inv);
    o.y = (unsigned short)f2bf(v.y * inv);
    o.z = (unsigned short)f2bf(v.z * inv);
    o.w = (unsigned short)f2bf(v.w * inv);
    ((ushort4*)(ebf + (size_t)row * DIM))[tid] = o;
    if (tid == 0) sumexpz[row] = 0.0f;
}

// ---------------- kernel 1b: W fp32 -> bf16 + inv-norms (ONE pass) ---------
__global__ void k_wconv(const float* __restrict__ w, short* __restrict__ wbf,
                        float* __restrict__ wnorm) {
    int tid = threadIdx.x;          // 256 = 4 waves
    int wv = tid >> 6, lane = tid & 63;
    int row = blockIdx.x * 4 + wv;  // grid 25000 -> rows 0..99999
    const float4* src = (const float4*)(w + (size_t)row * DIM);
    float4 a = src[lane];
    float4 b = src[64 + lane];
    float ssq = a.x * a.x + a.y * a.y + a.z * a.z + a.w * a.w +
                b.x * b.x + b.y * b.y + b.z * b.z + b.w * b.w;
#pragma unroll
    for (int m = 1; m < 64; m <<= 1) ssq += __shfl_xor(ssq, m, 64);
    ushort4 oa, ob;
    oa.x = (unsigned short)f2bf(a.x);
    oa.y = (unsigned short)f2bf(a.y);
    oa.z = (unsigned short)f2bf(a.z);
    oa.w = (unsigned short)f2bf(a.w);
    ob.x = (unsigned short)f2bf(b.x);
    ob.y = (unsigned short)f2bf(b.y);
    ob.z = (unsigned short)f2bf(b.z);
    ob.w = (unsigned short)f2bf(b.w);
    ushort4* dst = (ushort4*)(wbf + (size_t)row * DIM);
    dst[lane] = oa;
    dst[64 + lane] = ob;
    if (lane == 0) wnorm[row] = 1.0f / fmaxf(sqrtf(ssq), 1e-12f);
}

// ---------------- kernel 2: pure-DMA GEMM + margin + partial sums ----------
// 128x256 tile, 512 threads (8 waves as 2M x 4N; wave tile 64x64 — per-wave
// structure IDENTICAL to round 3: 16 MFMA/kc, same swizzle, same frag reads).
// BK=32, 3-buffer rotation, counted vmcnt(3) (3 gld_lds16 per wave per kc:
// 1 A + 2 B), one barrier per kc. vs round 3: occupancy 12 -> 16 waves/CU
// (LDS 72.5KB -> 2 blocks/CU), barrier+prologue overhead per output halved,
// staged traffic 800 -> 600 MB. Epilogue: plain partial stores (no atomics).
__global__ __launch_bounds__(512, 4) void k_gemm2(
    const short* __restrict__ ebf, const short* __restrict__ wbf,
    const float* __restrict__ wnorm, const int* __restrict__ labels,
    float* __restrict__ partial, float* __restrict__ phiS) {
    __shared__ __align__(16) short As[3][4096];  // 3 x 8KB  (128 rows)
    __shared__ __align__(16) short Bs[3][8192];  // 3 x 16KB (256 rows)
    __shared__ int sLbl[128];

    int bx = blockIdx.x;
    int nb = (bx >> 5) * 8 + (bx & 7);  // mb-siblings share bx%8 (same XCD)
    if (nb >= NB_TILES) return;
    int mb = (bx >> 3) & 3;
    int n0 = nb * 256;

    int tid = threadIdx.x;
    int lane = tid & 63;
    int wv = tid >> 6;           // 0..7
    int wm = wv >> 2, wn = wv & 3;
    int quad = lane >> 4, l16 = lane & 15;

    // --- staging addresses (per-lane global, pre-swizzled granule) ---
    // key reduces to lane-only ((l>>2)^(l>>4))&3 for any 16-aligned row base
    int g = (lane & 3) ^ (((lane >> 2) ^ (lane >> 4)) & 3);
    int r0 = wv * 16 + (lane >> 2);  // 0..127
    const char* gA = (const char*)ebf + (size_t)(mb * 128 + r0) * (DIM * 2) + g * 16;
    int wr0 = n0 + r0;       if (wr0 > NCLS - 1) wr0 = NCLS - 1;
    int wr1 = n0 + 128 + r0; if (wr1 > NCLS - 1) wr1 = NCLS - 1;
    const char* gB0 = (const char*)wbf + (size_t)wr0 * (DIM * 2) + g * 16;
    const char* gB1 = (const char*)wbf + (size_t)wr1 * (DIM * 2) + g * 16;
    int ldsw = wv * 1024;  // wave-uniform LDS byte base within a call region

#define STAGE(BUF, KC)                                                    \
    do {                                                                  \
        int kb_ = (KC) * 64;                                              \
        gld_lds16(gA + kb_, (char*)&As[BUF][0] + ldsw);                   \
        gld_lds16(gB0 + kb_, (char*)&Bs[BUF][0] + ldsw);                  \
        gld_lds16(gB1 + kb_, (char*)&Bs[BUF][0] + 8192 + ldsw);          \
    } while (0)

    // --- prologue: stage kc=0,1; drain kc=0 only (kc=1 stays in flight) ---
    STAGE(0, 0);
    STAGE(1, 1);

    if (tid < 128) sLbl[tid] = labels[mb * 128 + tid];

    f32x4 acc[4][4];
#pragma unroll
    for (int i = 0; i < 4; ++i)
#pragma unroll
        for (int j = 0; j < 4; ++j) acc[i][j] = (f32x4){0.f, 0.f, 0.f, 0.f};

    // --- fragment read bases (identical to round 3) ---
    int go = (quad ^ ((l16 ^ (l16 >> 2)) & 3)) * 8;
    int arowb = (wm * 64 + l16) * 32 + go;
    int browb = (wn * 64 + l16) * 32 + go;

    asm volatile("s_waitcnt vmcnt(3)\n\ts_barrier" ::: "memory");

#pragma unroll
    for (int kc = 0; kc < 16; ++kc) {
        int cur = kc % 3;
        if (kc + 2 < 16) STAGE((kc + 2) % 3, kc + 2);
        {
            bf16x8 af[4], bfr[4];
#pragma unroll
            for (int t = 0; t < 4; ++t)
                af[t] = *(const bf16x8*)&As[cur][arowb + t * 16 * 32];
#pragma unroll
            for (int t = 0; t < 4; ++t)
                bfr[t] = *(const bf16x8*)&Bs[cur][browb + t * 16 * 32];
#pragma unroll
            for (int tm = 0; tm < 4; ++tm)
#pragma unroll
                for (int tn = 0; tn < 4; ++tn)
                    acc[tm][tn] = __builtin_amdgcn_mfma_f32_16x16x32_bf16(
                        af[tm], bfr[tn], acc[tm][tn], 0, 0, 0);
        }
        if (kc < 15) {
            if (kc + 2 < 16)
                asm volatile("s_waitcnt vmcnt(3)\n\ts_barrier" ::: "memory");
            else
                asm volatile("s_waitcnt vmcnt(0)\n\ts_barrier" ::: "memory");
        }
    }
#undef STAGE

    // ---- w scales from precomputed norms ----
    float wscale[4];
#pragma unroll
    for (int tn = 0; tn < 4; ++tn) {
        int col = n0 + wn * 64 + tn * 16 + l16;
        if (col > NCLS - 1) col = NCLS - 1;
        wscale[tn] = wnorm[col];
    }

    // ---- epilogue: scale, clip, margin on label col, exp, per-row reduce --
    float rowsum[16];
#pragma unroll
    for (int i = 0; i < 16; ++i) rowsum[i] = 0.0f;

#pragma unroll
    for (int tm = 0; tm < 4; ++tm) {
#pragma unroll
        for (int r = 0; r < 4; ++r) {
            int m_local = wm * 64 + tm * 16 + quad * 4 + r;
            int lbl = sLbl[m_local];
            float rs = 0.0f;
#pragma unroll
            for (int tn = 0; tn < 4; ++tn) {
                float c = acc[tm][tn][r] * wscale[tn];
                c = fminf(fmaxf(c, CLIP_LO), CLIP_HI);
                int col = n0 + wn * 64 + tn * 16 + l16;
                float t = c;
                if (col == lbl) {
                    float sn = sqrtf(fmaxf(1.0f - c * c, 0.0f));
                    float ph = c * COS_M - sn * SIN_M;
                    ph = (c > TH_C) ? ph : (c - MM_C);
                    t = ph;
                    phiS[mb * 128 + m_local] = S_SCALE * ph;
                }
                float ex = (col < NCLS) ? __expf(S_SCALE * t - 64.0f) : 0.0f;
                rs += ex;
            }
            rowsum[tm * 4 + r] = rs;
        }
    }
    // plain stores: one float per (wave row); slot written exactly once
    float* pbase = partial + (size_t)(nb * 4 + wn) * 512 + mb * 128;
#pragma unroll
    for (int idx = 0; idx < 16; ++idx) {
        float v = rowsum[idx];
        v += __shfl_xor(v, 1, 64);
        v += __shfl_xor(v, 2, 64);
        v += __shfl_xor(v, 4, 64);
        v += __shfl_xor(v, 8, 64);
        if (l16 == idx) {
            int tm = idx >> 2, r = idx & 3;
            int m_local = wm * 64 + tm * 16 + quad * 4 + r;
            pbase[m_local] = v;
        }
    }
}

// ---------------- kernel 2b: reduce partials stage 1 (wide) ----------------
// 8192 threads: thread (seg, col) sums partial[p*512+col] over its ~98-slice.
// Coalesced: block b covers 256 consecutive cols of one seg.
__global__ void k_rownll(const float* __restrict__ partial,
                         float* __restrict__ part2) {
    int gid = blockIdx.x * 256 + threadIdx.x;  // grid 32 x 256
    int col = ((blockIdx.x & 1) << 8) | threadIdx.x;  // 0..511
    int seg = gid >> 9;                               // 0..15
    int p0 = seg * 98;
    int p1 = p0 + 98; if (p1 > NPART) p1 = NPART;
    float s = 0.0f;
#pragma unroll 4
    for (int p = p0; p < p1; ++p) s += partial[(size_t)p * 512 + col];
    part2[seg * 512 + col] = s;
}

// ---------------- kernel 3: finish sumexp + nll + mean ----------------
__global__ void k_final_mean(const float* __restrict__ part2,
                             const float* __restrict__ phiS,
                             float* __restrict__ out) {
    int tid = threadIdx.x;  // 512
    float s = 0.0f;
#pragma unroll
    for (int seg = 0; seg < 16; ++seg) s += part2[seg * 512 + tid];
    float nll = 64.0f + logf(s) - phiS[tid];
    for (int m = 1; m < 64; m <<= 1) nll += __shfl_xor(nll, m, 64);
    __shared__ float ws[8];
    if ((tid & 63) == 0) ws[tid >> 6] = nll;
    __syncthreads();
    if (tid == 0) {
        float t = 0.0f;
        for (int j = 0; j < 8; ++j) t += ws[j];
        out[0] = t / (float)BATCH;
    }
}

// ---------------- fallback: round-0 fused kernel (small workspace) ----------
__global__ __launch_bounds__(256, 2) void k_gemm_fb(
    const short* __restrict__ ebf, const float* __restrict__ wgt,
    const int* __restrict__ labels, float* __restrict__ sumexp,
    float* __restrict__ phiS) {
    __shared__ __align__(16) short As[128 * 32];
    __shared__ __align__(16) short Bs[128 * 32];
    __shared__ int sLbl[128];
    __shared__ float sWn[128];

    int bx = blockIdx.x;
    int nb = (bx >> 5) * 8 + (bx & 7);
    if (nb >= NB_TILES_FB) return;
    int mb = (bx >> 3) & 3;
    int n0 = nb * 128;

    int tid = threadIdx.x;
    int lane = tid & 63;
    int wv = tid >> 6;
    int wm = wv >> 1, wn = wv & 1;
    int quad = lane >> 4, l16 = lane & 15;

    if (tid < 128) sLbl[tid] = labels[mb * 128 + tid];

    int ar = tid >> 2;
    const short* gA = ebf + (size_t)(mb * 128 + ar) * DIM + (tid & 3) * 8;
    int akey = ((tid >> 2) ^ (tid >> 4)) & 3;
    int aw0 = ar * 32 + ((tid & 3) ^ akey) * 8;

    int br = tid >> 3;
    int gBo[4];
#pragma unroll
    for (int i = 0; i < 4; ++i) {
        int wr = n0 + 32 * i + br;
        if (wr > NCLS - 1) wr = NCLS - 1;
        gBo[i] = wr * DIM + (tid & 7) * 4;
    }
    int bkey = ((tid >> 3) ^ (tid >> 5)) & 3;
    int bw0 = br * 32 + (((tid & 7) >> 1) ^ bkey) * 8 + (tid & 1) * 4;

    f32x4 acc[4][4];
#pragma unroll
    for (int i = 0; i < 4; ++i)
#pragma unroll
        for (int j = 0; j < 4; ++j) acc[i][j] = (f32x4){0.f, 0.f, 0.f, 0.f};
    float ssq[4] = {0.f, 0.f, 0.f, 0.f};

    int go = (quad ^ ((l16 ^ (l16 >> 2)) & 3)) * 8;
    int arowb = (wm * 64 + l16) * 32 + go;
    int browb = (wn * 64 + l16) * 32 + go;

    int4 ra0 = *(const int4*)(gA);
    int4 ra1 = *(const int4*)(gA + 64 * DIM);
    float4 rb0 = *(const float4*)(wgt + gBo[0]);
    float4 rb1 = *(const float4*)(wgt + gBo[1]);
    float4 rb2 = *(const float4*)(wgt + gBo[2]);
    float4 rb3 = *(const float4*)(wgt + gBo[3]);

#pragma unroll 1
    for (int kc = 0; kc < 16; ++kc) {
        *(int4*)&As[aw0] = ra0;
        *(int4*)&As[64 * 32 + aw0] = ra1;
        {
            uint2 p;
            ssq[0] += rb0.x * rb0.x + rb0.y * rb0.y + rb0.z * rb0.z + rb0.w * rb0.w;
            p.x = pack2(rb0.x, rb0.y); p.y = pack2(rb0.z, rb0.w);
            *(uint2*)&Bs[bw0] = p;
            ssq[1] += rb1.x * rb1.x + rb1.y * rb1.y + rb1.z * rb1.z + rb1.w * rb1.w;
            p.x = pack2(rb1.x, rb1.y); p.y = pack2(rb1.z, rb1.w);
            *(uint2*)&Bs[1024 + bw0] = p;
            ssq[2] += rb2.x * rb2.x + rb2.y * rb2.y + rb2.z * rb2.z + rb2.w * rb2.w;
            p.x = pack2(rb2.x, rb2.y); p.y = pack2(rb2.z, rb2.w);
            *(uint2*)&Bs[2048 + bw0] = p;
            ssq[3] += rb3.x * rb3.x + rb3.y * rb3.y + rb3.z * rb3.z + rb3.w * rb3.w;
            p.x = pack2(rb3.x, rb3.y); p.y = pack2(rb3.z, rb3.w);
            *(uint2*)&Bs[3072 + bw0] = p;
        }
        if (kc < 15) {
            int ko = (kc + 1) * 32;
            ra0 = *(const int4*)(gA + ko);
            ra1 = *(const int4*)(gA + 64 * DIM + ko);
            rb0 = *(const float4*)(wgt + gBo[0] + ko);
            rb1 = *(const float4*)(wgt + gBo[1] + ko);
            rb2 = *(const float4*)(wgt + gBo[2] + ko);
            rb3 = *(const float4*)(wgt + gBo[3] + ko);
        }
        asm volatile("s_waitcnt lgkmcnt(0)\n\ts_barrier" ::: "memory");
        {
            bf16x8 af[4], bfr[4];
#pragma unroll
            for (int t = 0; t < 4; ++t)
                af[t] = *(const bf16x8*)&As[arowb + t * 16 * 32];
#pragma unroll
            for (int t = 0; t < 4; ++t)
                bfr[t] = *(const bf16x8*)&Bs[browb + t * 16 * 32];
#pragma unroll
            for (int tm = 0; tm < 4; ++tm)
#pragma unroll
                for (int tn = 0; tn < 4; ++tn)
                    acc[tm][tn] = __builtin_amdgcn_mfma_f32_16x16x32_bf16(
                        af[tm], bfr[tn], acc[tm][tn], 0, 0, 0);
        }
        asm volatile("s_barrier" ::: "memory");
    }

#pragma unroll
    for (int i = 0; i < 4; ++i) {
        float s = ssq[i];
        s += __shfl_xor(s, 1, 64);
        s += __shfl_xor(s, 2, 64);
        s += __shfl_xor(s, 4, 64);
        if ((lane & 7) == 0)
            sWn[32 * i + br] = 1.0f / fmaxf(sqrtf(s), 1e-12f);
    }
    asm volatile("s_waitcnt lgkmcnt(0)\n\ts_barrier" ::: "memory");

    float wscale[4];
#pragma unroll
    for (int tn = 0; tn < 4; ++tn) wscale[tn] = sWn[wn * 64 + tn * 16 + l16];

    float rowsum[16];
#pragma unroll
    for (int i = 0; i < 16; ++i) rowsum[i] = 0.0f;

#pragma unroll
    for (int tm = 0; tm < 4; ++tm) {
#pragma unroll
        for (int r = 0; r < 4; ++r) {
            int m_local = wm * 64 + tm * 16 + quad * 4 + r;
            int lbl = sLbl[m_local];
            float rs = 0.0f;
#pragma unroll
            for (int tn = 0; tn < 4; ++tn) {
                float c = acc[tm][tn][r] * wscale[tn];
                c = fminf(fmaxf(c, CLIP_LO), CLIP_HI);
                int col = n0 + wn * 64 + tn * 16 + l16;
                float t = c;
                if (col == lbl) {
                    float sn = sqrtf(fmaxf(1.0f - c * c, 0.0f));
                    float ph = c * COS_M - sn * SIN_M;
                    ph = (c > TH_C) ? ph : (c - MM_C);
                    t = ph;
                    phiS[mb * 128 + m_local] = S_SCALE * ph;
                }
                float ex = (col < NCLS) ? __expf(S_SCALE * t - 64.0f) : 0.0f;
                rs += ex;
            }
            rowsum[tm * 4 + r] = rs;
        }
    }
#pragma unroll
    for (int idx = 0; idx < 16; ++idx) {
        float v = rowsum[idx];
        v += __shfl_xor(v, 1, 64);
        v += __shfl_xor(v, 2, 64);
        v += __shfl_xor(v, 4, 64);
        v += __shfl_xor(v, 8, 64);
        if (l16 == idx) {
            int tm = idx >> 2, r = idx & 3;
            int m_local = wm * 64 + tm * 16 + quad * 4 + r;
            atomicAdd(&sumexp[mb * 128 + m_local], v);
        }
    }
}

__global__ void k_final_fb(const float* __restrict__ sumexp,
                           const float* __restrict__ phiS,
                           float* __restrict__ out) {
    int tid = threadIdx.x;  // 512
    float nll = 64.0f + logf(sumexp[tid]) - phiS[tid];
    for (int m = 1; m < 64; m <<= 1) nll += __shfl_xor(nll, m, 64);
    __shared__ float ws[8];
    if ((tid & 63) == 0) ws[tid >> 6] = nll;
    __syncthreads();
    if (tid == 0) {
        float s = 0.0f;
        for (int j = 0; j < 8; ++j) s += ws[j];
        out[0] = s / (float)BATCH;
    }
}

// ---------------- launch ----------------
extern "C" void kernel_launch(void* const* d_in, const int* in_sizes, int n_in,
                              void* d_out, int out_size, void* d_ws,
                              size_t ws_size, hipStream_t stream) {
    const float* emb = (const float*)d_in[0];
    const float* wgt = (const float*)d_in[1];
    const int* lbl = (const int*)d_in[2];

    char* ws = (char*)d_ws;
    short* ebf = (short*)ws;                   // 524,288 B
    float* phiS = (float*)(ws + 524288);       // 2,048 B
    float* sumexp_fb = (float*)(ws + 526336);  // 2,048 B
    float* part2 = (float*)(ws + 528384);      // 32,768 B -> ends 561,152
    float* wnorm = (float*)(ws + 561152);      // 400,000 B -> ends 961,152
    float* partial = (float*)(ws + 1048576);   // 3,203,072 B -> ends 4,251,648
    short* wbf = (short*)(ws + 4251648);       // 102,400,000 B

    const size_t NEED = 4251648ull + 102400000ull;

    if (ws_size >= NEED) {
        k_wconv<<<dim3(NCLS / 4), dim3(256), 0, stream>>>(wgt, wbf, wnorm);
        k_norm_e<<<dim3(BATCH), dim3(128), 0, stream>>>(emb, ebf, sumexp_fb);
        k_gemm2<<<dim3(1568), dim3(512), 0, stream>>>(ebf, wbf, wnorm, lbl,
                                                      partial, phiS);
        k_rownll<<<dim3(32), dim3(256), 0, stream>>>(partial, part2);
        k_final_mean<<<dim3(1), dim3(512), 0, stream>>>(part2, phiS,
                                                        (float*)d_out);
    } else {
        k_norm_e<<<dim3(BATCH), dim3(128), 0, stream>>>(emb, ebf, sumexp_fb);
        k_gemm_fb<<<dim3(3136), dim3(256), 0, stream>>>(ebf, wgt, lbl,
                                                        sumexp_fb, phiS);
        k_final_fb<<<dim3(1), dim3(512), 0, stream>>>(sumexp_fb, phiS,
                                                      (float*)d_out);
    }
}